// Round 9
// baseline (74.977 us; speedup 1.0000x reference)
//
#include <hip/hip_runtime.h>
#include <hip/hip_bf16.h>

typedef __attribute__((ext_vector_type(8))) short bf16x8;
typedef __attribute__((ext_vector_type(4))) float f32x4;

#define NB 32
#define NO 256
#define XS_BYTES (6 * 30 * 512)   // 92160 B x-slab (6 rows x 30 cols x 256ch bf16)

static __device__ __forceinline__ void gld16(const void* g, void* l) {
    __builtin_amdgcn_global_load_lds(
        (const __attribute__((address_space(1))) void*)g,
        (__attribute__((address_space(3))) void*)l, 16, 0, 0);
}

// Fused prep: blocks [0,288) build wrt; blocks [288, 288+3840) build xp.
// wrt layout, groups of 8 shorts: [s=tap*4+ic][kw2][mw][mf][klo][kcol][e8]
__global__ void prep_kernel(const float* __restrict__ w2, __hip_bfloat16* __restrict__ wrt,
                            const float* __restrict__ x, __hip_bfloat16* __restrict__ xp) {
    if (blockIdx.x < 288) {
        int idx = blockIdx.x * 256 + threadIdx.x;   // group id in [0, 73728)
        int kcol = idx & 15;
        int klo = (idx >> 4) & 3;
        int mf = (idx >> 6) & 3;
        int mw = (idx >> 8) & 3;
        int kw2 = (idx >> 10) & 1;
        int s = idx >> 11;            // 0..35
        int tap = s >> 2;
        int ic = s & 3;
        int o = mw * 64 + mf * 16 + kcol;
        int ch = kw2 * 128 + ic * 32 + klo * 8;
        const float* src = w2 + (size_t)o * 2304 + (size_t)ch * 9 + tap;
        union { bf16x8 v; __hip_bfloat16 e[8]; } u;
#pragma unroll
        for (int e = 0; e < 8; ++e) u.e[e] = __float2bfloat16(src[e * 9]);
        *(bf16x8*)((short*)wrt + (size_t)idx * 8) = u.v;
        return;
    }
    __shared__ float tile[64][29];
    int blk = blockIdx.x - 288;
    int icnk = blk & 3;
    int t = blk >> 2;
    int pr = t % 30;
    int b = t / 30;
    int i0 = icnk * 64;
    __hip_bfloat16* dst = xp + ((size_t)(b * 30 + pr) * 30) * 256 + i0;
    const bf16x8 z = (bf16x8){0, 0, 0, 0, 0, 0, 0, 0};
    if (pr == 0 || pr == 29) {
        for (int e = threadIdx.x; e < 30 * 8; e += 256) {
            int q = e >> 3, part = e & 7;
            *(bf16x8*)((short*)(dst + (size_t)q * 256) + part * 8) = z;
        }
        return;
    }
    int p = pr - 1;
    for (int e = threadIdx.x; e < 64 * 28; e += 256) {
        int ii = e / 28, q = e % 28;
        tile[ii][q] = x[((b * 256 + i0 + ii) * 28 + p) * 28 + q];
    }
    __syncthreads();
    for (int e = threadIdx.x; e < 28 * 64; e += 256) {
        int q = e >> 6, ii = e & 63;
        dst[(size_t)(q + 1) * 256 + ii] = __float2bfloat16(tile[ii][q]);
    }
    if (threadIdx.x < 16) {
        int col = (threadIdx.x >> 3) * 29, part = threadIdx.x & 7;
        *(bf16x8*)((short*)(dst + (size_t)col * 256) + part * 8) = z;
    }
}

#define MM(A_, B_, mf_, nf_) \
    acc[mf_][nf_] = __builtin_amdgcn_mfma_f32_16x16x32_bf16(A_, B_, acc[mf_][nf_], 0, 0, 0);

#define CLUSTER(A0, A1, A2, A3, B0, B1, B2, B3, B4, B5, B6)             \
    __builtin_amdgcn_s_setprio(1);                                      \
    MM(A0, B0, 0, 0) MM(A1, B0, 1, 0) MM(A2, B0, 2, 0) MM(A3, B0, 3, 0) \
    MM(A0, B1, 0, 1) MM(A1, B1, 1, 1) MM(A2, B1, 2, 1) MM(A3, B1, 3, 1) \
    MM(A0, B2, 0, 2) MM(A1, B2, 1, 2) MM(A2, B2, 2, 2) MM(A3, B2, 3, 2) \
    MM(A0, B3, 0, 3) MM(A1, B3, 1, 3) MM(A2, B3, 2, 3) MM(A3, B3, 3, 3) \
    MM(A0, B4, 0, 4) MM(A1, B4, 1, 4) MM(A2, B4, 2, 4) MM(A3, B4, 3, 4) \
    MM(A0, B5, 0, 5) MM(A1, B5, 1, 5) MM(A2, B5, 2, 5) MM(A3, B5, 3, 5) \
    MM(A0, B6, 0, 6) MM(A1, B6, 1, 6) MM(A2, B6, 2, 6) MM(A3, B6, 3, 6) \
    __builtin_amdgcn_s_setprio(0);

#define LOADB(D0, D1, D2, D3, D4, D5, D6, XO)                                  \
    D0 = *(const bf16x8*)(Xs + ((u[0] ^ ((kk[0] & 7u) << 4)) ^ (XO)));         \
    D1 = *(const bf16x8*)(Xs + ((u[1] ^ ((kk[1] & 7u) << 4)) ^ (XO)));         \
    D2 = *(const bf16x8*)(Xs + ((u[2] ^ ((kk[2] & 7u) << 4)) ^ (XO)));         \
    D3 = *(const bf16x8*)(Xs + ((u[3] ^ ((kk[3] & 7u) << 4)) ^ (XO)));         \
    D4 = *(const bf16x8*)(Xs + ((u[4] ^ ((kk[4] & 7u) << 4)) ^ (XO)));         \
    D5 = *(const bf16x8*)(Xs + ((u[5] ^ ((kk[5] & 7u) << 4)) ^ (XO)));         \
    D6 = *(const bf16x8*)(Xs + ((u[6] ^ ((kk[6] & 7u) << 4)) ^ (XO)));

#define PHASE(ICV, XOv)                                                        \
    {                                                                          \
        if ((ICV) != 3 || tap < 8) {                                           \
            char* l = AbW + ((((ICV) + 1) & 1) * 4096);                        \
            gld16(pG, l);                                                      \
            gld16(pG + 1024, l + 1024);                                        \
            gld16(pG + 2048, l + 2048);                                        \
            gld16(pG + 3072, l + 3072);                                        \
            pG += 32768;                                                       \
        }                                                                      \
        bf16x8 bv0, bv1, bv2, bv3, bv4, bv5, bv6;                              \
        LOADB(bv0, bv1, bv2, bv3, bv4, bv5, bv6, XOv)                          \
        if ((ICV) == 3 && tap == 8) {                                          \
            asm volatile("s_waitcnt vmcnt(0)" ::: "memory");                   \
        } else {                                                               \
            asm volatile("s_waitcnt vmcnt(4)" ::: "memory");                   \
        }                                                                      \
        const char* ar = AbR + (((ICV) & 1) * 4096);                           \
        bf16x8 a0 = *(const bf16x8*)(ar);                                      \
        bf16x8 a1 = *(const bf16x8*)(ar + 1024);                               \
        bf16x8 a2 = *(const bf16x8*)(ar + 2048);                               \
        bf16x8 a3 = *(const bf16x8*)(ar + 3072);                               \
        CLUSTER(a0, a1, a2, a3, bv0, bv1, bv2, bv3, bv4, bv5, bv6)             \
    }

// Shared prologue/epilogue body. K-loop differs: real path (full memory pipeline)
// vs MFMA-only probe (operands loaded once, pure back-to-back clusters).
template <int PROBE>
__global__ __launch_bounds__(512, 2) void conv_body(
    const __hip_bfloat16* __restrict__ xp, const __hip_bfloat16* __restrict__ wrt,
    const float* __restrict__ xg, const float* __restrict__ w1,
    const float* __restrict__ b1, float* __restrict__ out) {
    __shared__ __align__(16) char Xs[XS_BYTES];      // 92160
    __shared__ __align__(16) char Ab[8 * 2 * 4096];  // 65536
    __shared__ float hsm[512];                       // 2048  -> 159744 total
    const int bid = blockIdx.x;
    const int v = (bid & 7) * 28 + (bid >> 3);
    const int b = v / 7;
    const int nt = v - b * 7;
    const int tid = threadIdx.x;
    const int lane = tid & 63;
    const int wv = tid >> 6;
    const int mw = wv & 3;
    const int kw2 = wv >> 2;
    const int kcol = lane & 15;
    const int klo = lane >> 4;

    const char* wrtc = (const char*)wrt;
    char* AbW = Ab + wv * 8192;
    const char* AbR = Ab + wv * 8192 + lane * 16;
    const char* pG0 = wrtc + wv * 4096 + lane * 16;

    gld16(pG0, AbW);
    gld16(pG0 + 1024, AbW + 1024);
    gld16(pG0 + 2048, AbW + 2048);
    gld16(pG0 + 3072, AbW + 3072);
    const char* pG = pG0 + 32768;

    {
        float s = b1[tid];
        const float* g = xg + b * 16;
        const float* w = w1 + tid * 16;
#pragma unroll
        for (int c = 0; c < 16; ++c) s += g[c] * w[c];
        hsm[tid] = 1.0f / (1.0f + expf(-s));
    }

    {
        const char* src = (const char*)(xp + ((size_t)b * 900 + nt * 120) * 256);
        for (int c = tid; c < 5760; c += 512) {
            int sp = c >> 5, w = c & 31;
            int rr = sp / 30;
            int qq = sp - rr * 30;
            int key = (qq + 4 * rr) & 7;
            *(bf16x8*)(Xs + sp * 512 + ((w ^ key) << 4)) = *(const bf16x8*)(src + (size_t)c * 16);
        }
    }
    __syncthreads();

    unsigned u[7], kk[7];
#pragma unroll
    for (int nf = 0; nf < 7; ++nf) {
        int n = nf * 16 + kcol;
        int r0 = n / 28;
        int q0 = n - r0 * 28;
        u[nf] = (unsigned)((r0 * 30 + q0) * 512 + (klo << 4));
        kk[nf] = (unsigned)(q0 + 4 * r0);
    }
    const unsigned xo0 = (unsigned)((kw2 * 4 + 0) << 6);
    const unsigned xo1 = (unsigned)((kw2 * 4 + 1) << 6);
    const unsigned xo2 = (unsigned)((kw2 * 4 + 2) << 6);
    const unsigned xo3 = (unsigned)((kw2 * 4 + 3) << 6);

    f32x4 acc[4][7];
#pragma unroll
    for (int mf = 0; mf < 4; ++mf)
#pragma unroll
        for (int nf = 0; nf < 7; ++nf) acc[mf][nf] = (f32x4){0.f, 0.f, 0.f, 0.f};

    if (PROBE) {
        // MFMA-only: load one real operand set, then 36 pure clusters.
        bf16x8 bv0, bv1, bv2, bv3, bv4, bv5, bv6;
        LOADB(bv0, bv1, bv2, bv3, bv4, bv5, bv6, xo0)
        const char* ar = AbR;
        bf16x8 a0 = *(const bf16x8*)(ar);
        bf16x8 a1 = *(const bf16x8*)(ar + 1024);
        bf16x8 a2 = *(const bf16x8*)(ar + 2048);
        bf16x8 a3 = *(const bf16x8*)(ar + 3072);
        asm volatile("s_waitcnt vmcnt(0) lgkmcnt(0)" ::: "memory");
#pragma unroll 1
        for (int tap = 0; tap < 9; ++tap) {
            CLUSTER(a0, a1, a2, a3, bv0, bv1, bv2, bv3, bv4, bv5, bv6)
            CLUSTER(a0, a1, a2, a3, bv0, bv1, bv2, bv3, bv4, bv5, bv6)
            CLUSTER(a0, a1, a2, a3, bv0, bv1, bv2, bv3, bv4, bv5, bv6)
            CLUSTER(a0, a1, a2, a3, bv0, bv1, bv2, bv3, bv4, bv5, bv6)
        }
    } else {
        for (int tap = 0; tap < 9; ++tap) {
            PHASE(0, xo0)
            PHASE(1, xo1)
            PHASE(2, xo2)
            PHASE(3, xo3)
            if (tap < 8) {
                const int cross = (tap == 2 || tap == 5);
                const unsigned da = cross ? 28u * 512u : 512u;
                const unsigned dk = cross ? 2u : 1u;
#pragma unroll
                for (int nf = 0; nf < 7; ++nf) { u[nf] += da; kk[nf] += dk; }
            }
        }
    }

    // epilogue: combine k-halves through LDS (Xs is dead), 2 rounds of 2 m-frags.
    __syncthreads();
    float* Xf = (float*)Xs;
#pragma unroll
    for (int r2 = 0; r2 < 2; ++r2) {
        if (kw2 == 1) {
#pragma unroll
            for (int mfi = 0; mfi < 2; ++mfi) {
                const int mf = r2 * 2 + mfi;
#pragma unroll
                for (int nf = 0; nf < 7; ++nf) {
#pragma unroll
                    for (int rr = 0; rr < 4; ++rr) {
                        int o = mw * 64 + mf * 16 + klo * 4 + rr;
                        int idx = (((mw * 2 + mfi) * 7 + nf) * 4 + rr) * 64 + lane;
                        Xf[idx] = hsm[2 * o + 1] * acc[mf][nf][rr];
                    }
                }
            }
        }
        __syncthreads();
        if (kw2 == 0) {
#pragma unroll
            for (int mfi = 0; mfi < 2; ++mfi) {
                const int mf = r2 * 2 + mfi;
#pragma unroll
                for (int nf = 0; nf < 7; ++nf) {
#pragma unroll
                    for (int rr = 0; rr < 4; ++rr) {
                        int o = mw * 64 + mf * 16 + klo * 4 + rr;
                        int idx = (((mw * 2 + mfi) * 7 + nf) * 4 + rr) * 64 + lane;
                        float y = hsm[2 * o] * acc[mf][nf][rr] + Xf[idx];
                        out[((size_t)b * NO + o) * 784 + nt * 112 + nf * 16 + kcol] = y;
                    }
                }
            }
        }
        __syncthreads();
    }
}

extern "C" void kernel_launch(void* const* d_in, const int* in_sizes, int n_in,
                              void* d_out, int out_size, void* d_ws, size_t ws_size,
                              hipStream_t stream) {
    const float* x = (const float*)d_in[0];
    const float* xg = (const float*)d_in[1];
    const float* w1 = (const float*)d_in[2];
    const float* b1 = (const float*)d_in[3];
    const float* w2 = (const float*)d_in[4];
    float* out = (float*)d_out;

    char* ws = (char*)d_ws;
    __hip_bfloat16* wrt = (__hip_bfloat16*)ws;                // 1,179,648 B
    __hip_bfloat16* xp = (__hip_bfloat16*)(ws + 1179648);     // 14,745,600 B
    float* probe_out = (float*)(ws + (size_t)16 * 1024 * 1024);  // 25.7 MB scratch sink

    prep_kernel<<<288 + NB * 30 * 4, 256, 0, stream>>>(w2, wrt, x, xp);
    conv_body<1><<<224, 512, 0, stream>>>(xp, wrt, xg, w1, b1, probe_out);  // timing probe
    conv_body<0><<<224, 512, 0, stream>>>(xp, wrt, xg, w1, b1, out);        // real
}

// Round 11
// 49.871 us; speedup vs baseline: 1.5034x; 1.5034x over previous
//
#include <hip/hip_runtime.h>
#include <hip/hip_bf16.h>

typedef __attribute__((ext_vector_type(8))) short bf16x8;
typedef __attribute__((ext_vector_type(4))) float f32x4;

#define NB 32
#define NO 256
#define XS_BYTES (6 * 30 * 512)   // 92160 B x-slab (6 rows x 30 cols x 256ch bf16)

static __device__ __forceinline__ void gld16(const void* g, void* l) {
    __builtin_amdgcn_global_load_lds(
        (const __attribute__((address_space(1))) void*)g,
        (__attribute__((address_space(3))) void*)l, 16, 0, 0);
}

// Fused prep: blocks [0,288) build wrt; blocks [288, 288+3840) build xp.
// wrt layout, groups of 8 shorts: [s=tap*4+ic][kw2][mw][mf][klo][kcol][e8]
// -> per (step, wave=kw2*4+mw) one contiguous 4096B block, lane-linear.
__global__ void prep_kernel(const float* __restrict__ w2, __hip_bfloat16* __restrict__ wrt,
                            const float* __restrict__ x, __hip_bfloat16* __restrict__ xp) {
    if (blockIdx.x < 288) {
        int idx = blockIdx.x * 256 + threadIdx.x;   // group id in [0, 73728)
        int kcol = idx & 15;
        int klo = (idx >> 4) & 3;
        int mf = (idx >> 6) & 3;
        int mw = (idx >> 8) & 3;
        int kw2 = (idx >> 10) & 1;
        int s = idx >> 11;            // 0..35
        int tap = s >> 2;
        int ic = s & 3;
        int o = mw * 64 + mf * 16 + kcol;
        int ch = kw2 * 128 + ic * 32 + klo * 8;
        const float* src = w2 + (size_t)o * 2304 + (size_t)ch * 9 + tap;
        union { bf16x8 v; __hip_bfloat16 e[8]; } u;
#pragma unroll
        for (int e = 0; e < 8; ++e) u.e[e] = __float2bfloat16(src[e * 9]);
        *(bf16x8*)((short*)wrt + (size_t)idx * 8) = u.v;
        return;
    }
    __shared__ float tile[64][29];
    int blk = blockIdx.x - 288;
    int icnk = blk & 3;
    int t = blk >> 2;
    int pr = t % 30;
    int b = t / 30;
    int i0 = icnk * 64;
    __hip_bfloat16* dst = xp + ((size_t)(b * 30 + pr) * 30) * 256 + i0;
    const bf16x8 z = (bf16x8){0, 0, 0, 0, 0, 0, 0, 0};
    if (pr == 0 || pr == 29) {
        for (int e = threadIdx.x; e < 30 * 8; e += 256) {
            int q = e >> 3, part = e & 7;
            *(bf16x8*)((short*)(dst + (size_t)q * 256) + part * 8) = z;
        }
        return;
    }
    int p = pr - 1;
    for (int e = threadIdx.x; e < 64 * 28; e += 256) {
        int ii = e / 28, q = e % 28;
        tile[ii][q] = x[((b * 256 + i0 + ii) * 28 + p) * 28 + q];
    }
    __syncthreads();
    for (int e = threadIdx.x; e < 28 * 64; e += 256) {
        int q = e >> 6, ii = e & 63;
        dst[(size_t)(q + 1) * 256 + ii] = __float2bfloat16(tile[ii][q]);
    }
    if (threadIdx.x < 16) {
        int col = (threadIdx.x >> 3) * 29, part = threadIdx.x & 7;
        *(bf16x8*)((short*)(dst + (size_t)col * 256) + part * 8) = z;
    }
}

#define MM(A_, B_, mf_, nf_) \
    acc[mf_][nf_] = __builtin_amdgcn_mfma_f32_16x16x32_bf16(A_, B_, acc[mf_][nf_], 0, 0, 0);

#define CLUSTER(A0, A1, A2, A3, B0, B1, B2, B3, B4, B5, B6)             \
    __builtin_amdgcn_s_setprio(1);                                      \
    MM(A0, B0, 0, 0) MM(A1, B0, 1, 0) MM(A2, B0, 2, 0) MM(A3, B0, 3, 0) \
    MM(A0, B1, 0, 1) MM(A1, B1, 1, 1) MM(A2, B1, 2, 1) MM(A3, B1, 3, 1) \
    MM(A0, B2, 0, 2) MM(A1, B2, 1, 2) MM(A2, B2, 2, 2) MM(A3, B2, 3, 2) \
    MM(A0, B3, 0, 3) MM(A1, B3, 1, 3) MM(A2, B3, 2, 3) MM(A3, B3, 3, 3) \
    MM(A0, B4, 0, 4) MM(A1, B4, 1, 4) MM(A2, B4, 2, 4) MM(A3, B4, 3, 4) \
    MM(A0, B5, 0, 5) MM(A1, B5, 1, 5) MM(A2, B5, 2, 5) MM(A3, B5, 3, 5) \
    MM(A0, B6, 0, 6) MM(A1, B6, 1, 6) MM(A2, B6, 2, 6) MM(A3, B6, 3, 6) \
    __builtin_amdgcn_s_setprio(0);

#define LOADB(D0, D1, D2, D3, D4, D5, D6, XO)                                  \
    D0 = *(const bf16x8*)(Xs + ((u[0] ^ ((kk[0] & 7u) << 4)) ^ (XO)));         \
    D1 = *(const bf16x8*)(Xs + ((u[1] ^ ((kk[1] & 7u) << 4)) ^ (XO)));         \
    D2 = *(const bf16x8*)(Xs + ((u[2] ^ ((kk[2] & 7u) << 4)) ^ (XO)));         \
    D3 = *(const bf16x8*)(Xs + ((u[3] ^ ((kk[3] & 7u) << 4)) ^ (XO)));         \
    D4 = *(const bf16x8*)(Xs + ((u[4] ^ ((kk[4] & 7u) << 4)) ^ (XO)));         \
    D5 = *(const bf16x8*)(Xs + ((u[5] ^ ((kk[5] & 7u) << 4)) ^ (XO)));         \
    D6 = *(const bf16x8*)(Xs + ((u[6] ^ ((kk[6] & 7u) << 4)) ^ (XO)));

// Depth-2 DMA phase for step s = tap*4 + ICV (buffer parity ICV&1):
//  1. vmcnt(4): stage(s) [issued 2 phases ago] landed; stage(s+1) stays in flight
//  2. A ds_read x4 from buf[s&1]
//  3. DMA-issue stage(s+2) into the SAME buffer (parity s+2 == s); safe WAR:
//     ds_reads issue first (aliasing orders them) and complete ~120cy, DMA lands >=400cy
//  4. B ds_read x7, then setprio'd 28-MFMA cluster (compiler inserts lgkm waits)
#define PHASE(ICV, XOv)                                                       \
    {                                                                         \
        asm volatile("s_waitcnt vmcnt(4)" ::: "memory");                      \
        const char* ar = AbR + (((ICV) & 1) * 4096);                          \
        bf16x8 a0 = *(const bf16x8*)(ar);                                     \
        bf16x8 a1 = *(const bf16x8*)(ar + 1024);                              \
        bf16x8 a2 = *(const bf16x8*)(ar + 2048);                              \
        bf16x8 a3 = *(const bf16x8*)(ar + 3072);                              \
        char* l = AbW + (((ICV) & 1) * 4096);                                 \
        gld16(pG, l);                                                         \
        gld16(pG + 1024, l + 1024);                                           \
        gld16(pG + 2048, l + 2048);                                           \
        gld16(pG + 3072, l + 3072);                                           \
        pG += 32768;                                                          \
        bf16x8 bv0, bv1, bv2, bv3, bv4, bv5, bv6;                             \
        LOADB(bv0, bv1, bv2, bv3, bv4, bv5, bv6, XOv)                         \
        CLUSTER(a0, a1, a2, a3, bv0, bv1, bv2, bv3, bv4, bv5, bv6)            \
    }

// Implicit-GEMM conv. 224 blocks (XCD-swizzled), 512 thr = 8 waves = (kw2*4+mw).
// Wave: 64 o x 112 n x its 128-ch half. Zero barriers in K-loop; A via per-wave
// global_load_lds double-buffer ring at pipeline depth 2 (counted vmcnt).
__global__ __launch_bounds__(512, 2) void conv_kernel(
    const __hip_bfloat16* __restrict__ xp, const __hip_bfloat16* __restrict__ wrt,
    const float* __restrict__ xg, const float* __restrict__ w1,
    const float* __restrict__ b1, float* __restrict__ out) {
    __shared__ __align__(16) char Xs[XS_BYTES];      // 92160
    __shared__ __align__(16) char Ab[8 * 2 * 4096];  // 65536
    __shared__ float hsm[512];                       // 2048  -> 159744 total
    const int bid = blockIdx.x;
    const int v = (bid & 7) * 28 + (bid >> 3);   // bijective XCD swizzle (224 % 8 == 0)
    const int b = v / 7;
    const int nt = v - b * 7;
    const int tid = threadIdx.x;
    const int lane = tid & 63;
    const int wv = tid >> 6;
    const int mw = wv & 3;
    const int kw2 = wv >> 2;
    const int kcol = lane & 15;
    const int klo = lane >> 4;

    const char* wrtc = (const char*)wrt;
    char* AbW = Ab + wv * 8192;                  // wave-uniform DMA dest base
    const char* AbR = Ab + wv * 8192 + lane * 16;
    const char* pG = wrtc + wv * 4096 + lane * 16;

    // stage steps 0 and 1 into buf0/buf1 (drained by the prologue __syncthreads)
    gld16(pG, AbW);
    gld16(pG + 1024, AbW + 1024);
    gld16(pG + 2048, AbW + 2048);
    gld16(pG + 3072, AbW + 3072);
    pG += 32768;
    gld16(pG, AbW + 4096);
    gld16(pG + 1024, AbW + 4096 + 1024);
    gld16(pG + 2048, AbW + 4096 + 2048);
    gld16(pG + 3072, AbW + 4096 + 3072);
    pG += 32768;                                 // next staged step = 2

    // h[j] = sigmoid(xg[b].w1[j] + b1[j])
    {
        float s = b1[tid];
        const float* g = xg + b * 16;
        const float* w = w1 + tid * 16;
#pragma unroll
        for (int c = 0; c < 16; ++c) s += g[c] * w[c];
        hsm[tid] = 1.0f / (1.0f + expf(-s));
    }

    // stage x-slab: linear coalesced global read; 16B chunk w of position sp stored at
    // sp*512 + ((w ^ key(sp))<<4), key(sp) = (q + 4r)&7 (conflict-free, 4*30 == 0 mod 8).
    {
        const char* src = (const char*)(xp + ((size_t)b * 900 + nt * 120) * 256);
        for (int c = tid; c < 5760; c += 512) {
            int sp = c >> 5, w = c & 31;
            int rr = sp / 30;
            int qq = sp - rr * 30;
            int key = (qq + 4 * rr) & 7;
            *(bf16x8*)(Xs + sp * 512 + ((w ^ key) << 4)) = *(const bf16x8*)(src + (size_t)c * 16);
        }
    }
    __syncthreads();   // drains vmcnt(0) + lgkmcnt(0): steps 0/1 DMA and Xs all ready

    // per-lane B geometry, incremental per-tap: u += dspv*512, kk += dkey
    unsigned u[7], kk[7];
#pragma unroll
    for (int nf = 0; nf < 7; ++nf) {
        int n = nf * 16 + kcol;
        int r0 = n / 28;
        int q0 = n - r0 * 28;
        u[nf] = (unsigned)((r0 * 30 + q0) * 512 + (klo << 4));
        kk[nf] = (unsigned)(q0 + 4 * r0);
    }
    const unsigned xo0 = (unsigned)((kw2 * 4 + 0) << 6);
    const unsigned xo1 = (unsigned)((kw2 * 4 + 1) << 6);
    const unsigned xo2 = (unsigned)((kw2 * 4 + 2) << 6);
    const unsigned xo3 = (unsigned)((kw2 * 4 + 3) << 6);

    f32x4 acc[4][7];
#pragma unroll
    for (int mf = 0; mf < 4; ++mf)
#pragma unroll
        for (int nf = 0; nf < 7; ++nf) acc[mf][nf] = (f32x4){0.f, 0.f, 0.f, 0.f};

    for (int tap = 0; tap < 9; ++tap) {
        PHASE(0, xo0)
        PHASE(1, xo1)
        PHASE(2, xo2)
        PHASE(3, xo3)
        if (tap < 8) {
            const int cross = (tap == 2 || tap == 5);
            const unsigned da = cross ? 28u * 512u : 512u;
            const unsigned dk = cross ? 2u : 1u;
#pragma unroll
            for (int nf = 0; nf < 7; ++nf) { u[nf] += da; kk[nf] += dk; }
        }
    }
    // tail stages (steps 36/37) read dead bytes past wrt into Ab -- never consumed,
    // drained by the epilogue barrier.

    // epilogue: combine k-halves through LDS (Xs is dead), 2 rounds of 2 m-frags.
    __syncthreads();
    float* Xf = (float*)Xs;
#pragma unroll
    for (int r2 = 0; r2 < 2; ++r2) {
        if (kw2 == 1) {
#pragma unroll
            for (int mfi = 0; mfi < 2; ++mfi) {
                const int mf = r2 * 2 + mfi;
#pragma unroll
                for (int nf = 0; nf < 7; ++nf) {
#pragma unroll
                    for (int rr = 0; rr < 4; ++rr) {
                        int o = mw * 64 + mf * 16 + klo * 4 + rr;
                        int idx = (((mw * 2 + mfi) * 7 + nf) * 4 + rr) * 64 + lane;
                        Xf[idx] = hsm[2 * o + 1] * acc[mf][nf][rr];
                    }
                }
            }
        }
        __syncthreads();
        if (kw2 == 0) {
#pragma unroll
            for (int mfi = 0; mfi < 2; ++mfi) {
                const int mf = r2 * 2 + mfi;
#pragma unroll
                for (int nf = 0; nf < 7; ++nf) {
#pragma unroll
                    for (int rr = 0; rr < 4; ++rr) {
                        int o = mw * 64 + mf * 16 + klo * 4 + rr;
                        int idx = (((mw * 2 + mfi) * 7 + nf) * 4 + rr) * 64 + lane;
                        float y = hsm[2 * o] * acc[mf][nf][rr] + Xf[idx];
                        out[((size_t)b * NO + o) * 784 + nt * 112 + nf * 16 + kcol] = y;
                    }
                }
            }
        }
        __syncthreads();
    }
}

extern "C" void kernel_launch(void* const* d_in, const int* in_sizes, int n_in,
                              void* d_out, int out_size, void* d_ws, size_t ws_size,
                              hipStream_t stream) {
    const float* x = (const float*)d_in[0];
    const float* xg = (const float*)d_in[1];
    const float* w1 = (const float*)d_in[2];
    const float* b1 = (const float*)d_in[3];
    const float* w2 = (const float*)d_in[4];
    float* out = (float*)d_out;

    char* ws = (char*)d_ws;
    __hip_bfloat16* wrt = (__hip_bfloat16*)ws;                // 1,179,648 B
    __hip_bfloat16* xp = (__hip_bfloat16*)(ws + 1179648);     // 14,745,600 B (tail-stage overrun lands here harmlessly)

    prep_kernel<<<288 + NB * 30 * 4, 256, 0, stream>>>(w2, wrt, x, xp);
    conv_kernel<<<224, 512, 0, stream>>>(xp, wrt, xg, w1, b1, out);
}